// Round 7
// baseline (2894.364 us; speedup 1.0000x reference)
//
#include <hip/hip_runtime.h>

// ---------------------------------------------------------------------------
// GLIFR RSNN on MI355X — round 7: r5 sync topology (PROVEN: the only one that
// runs on this harness), split-phase step to hide flag latency, XCD-local
// clusters, packed spb stores.
//
// History:
//   r1 (PASSED 11.75ms): counter barrier, 32 counters on ONE line -> MALL RMW
//      contention. r5 (PASSED 2.26ms): one 128B line per batch counter.
//   r2/r3/r4/r6 (ALL stub-signature failures): every alternative sync
//      construct (data-poll w/ sentinels, __syncthreads_and vote, per-lane
//      flag spins, __all-vote ring poll). r2/r3 had a real bug (fp32 S==0.0
//      exactly -> sentinel collision); r4/r6 audited clean yet still died.
//      RULE: keep tid0-only fetch_add+spin counter barrier, verbatim.
//   r7 changes (sync instructions untouched):
//      1. Split-phase: per step, the h1/GLIF-A half (depends only on S0 via
//         workspace, no inter-WG data) runs BEFORE the spin; the fetch_add
//         for step t is issued at end of t and flies while all WGs compute
//         step t+1's h1 block -> RMW latency hidden.
//      2. XCD-local: b = wg & 31, s = wg >> 5 -> a batch's 8 WGs share one
//         XCD (blockIdx % 8 round-robin), localizing counter+data traffic.
//      3. spb leaves as 2 packed 8B atomic stores per owner (same bytes).
//
// NOTE: fp32 S is EXACTLY 0.0 for strongly inhibited neurons (expf overflow
// -> 20/inf); and EXACTLY 20.0 for saturated ones. Never use output values
// as readiness sentinels.
// ---------------------------------------------------------------------------

#define T_STEPS 1000
#define NB 32
#define N0 256
#define N1 512

// fp32 constants, folded exactly like the reference's python-float scalars
#define C_SYN_D 0.95f                      // 1 - DT*KSYN
#define C_SYN_I 0.05f                      // DT*KSYN
#define C_V_D   0.99f                      // 1 - DT*KM
#define C_KMR   0.0010604453870625663f     // DT*KM*R
#define C_TH    10.986122886681098f        // SIGMA_V * log((20-5)/5)
#define C_A0_D  0.99985f                   // 1 - DT*0.003
#define C_A0_I  (-0.459f)                  // -9.18*1.0*DT
#define C_A1_D  0.995f                     // 1 - DT*0.1
#define C_A1_I  (-9.947f)                  // -198.94*1.0*DT

__device__ __forceinline__ float glif_S(float V) {
  // 20 * sigmoid((V - TH)/10)
  return 20.0f / (1.0f + __expf((C_TH - V) * 0.1f));
}

// ---------------------------------------------------------------------------
// Kernel A: layer-0 scan (unchanged from r5). grid = 128 x 64.
// ---------------------------------------------------------------------------
__global__ __launch_bounds__(64)
void layer0_scan(const float* __restrict__ x, float* __restrict__ S0) {
  const int g = blockIdx.x * 64 + threadIdx.x;
  float V = 0.f, a0 = 0.f, a1 = 0.f, Is = 0.f;
  float xb[8];
#pragma unroll
  for (int i = 0; i < 8; ++i) xb[i] = x[i * (NB * N0) + g];
#pragma unroll 1
  for (int tb = 0; tb < T_STEPS / 8; ++tb) {
#pragma unroll
    for (int u = 0; u < 8; ++u) {
      const int t = tb * 8 + u;
      const float xi = xb[u];
      const int tf = t + 8;
      if (tf < T_STEPS) xb[u] = x[tf * (NB * N0) + g];
      Is = fmaf(Is, C_SYN_D, C_SYN_I * xi);
      V  = fmaf(V, C_V_D, C_KMR * (Is + a0 + a1));
      const float S = glif_S(V);
      a0 = fmaf(a0, C_A0_D, C_A0_I * S);
      a1 = fmaf(a1, C_A1_D, C_A1_I * S);
      S0[t * (NB * N0) + g] = S;
    }
  }
}

// ---------------------------------------------------------------------------
// Kernel C: recurrence. grid = 256 x 256 (cooperative, 1 WG/CU).
// r7 mapping: b = wg & 31, s = wg >> 5  -> batch cluster on ONE XCD.
// tid = mg*16 + kc; per thread Wr 4m x 32k (32 float4), W1 4m x 16k (16).
// LDS staging padded: 32-word chunks at stride 36, 16-word at stride 20 ->
// stride-32 b128 reads are 2-way (free).
// ---------------------------------------------------------------------------
__global__ __launch_bounds__(256, 1)
void rsnn_recur(const float* __restrict__ W1, const float* __restrict__ Wr,
                const float* __restrict__ S0, float* __restrict__ out,
                unsigned* __restrict__ bar) {
  const int wg  = blockIdx.x;
  const int b   = wg & 31;     // r7: XCD-local cluster (blockIdx%8 == b%8)
  const int s   = wg >> 5;
  const int tid = threadIdx.x;
  const int mg  = tid >> 4;
  const int kc  = tid & 15;
  const int mBase = s * 64 + mg * 4;

  __shared__ float actS[16 * 36];   // 512 spb values, padded
  __shared__ float actO[16 * 20];   // 256 S0 values, padded

  // --- one-time weight load into registers ---
  float4 wr4[4][8];
  float4 w14[4][4];
#pragma unroll
  for (int i = 0; i < 4; ++i) {
    const float4* rw = (const float4*)(Wr + (size_t)(mBase + i) * N1 + kc * 32);
#pragma unroll
    for (int j = 0; j < 8; ++j) wr4[i][j] = rw[j];
    const float4* r1 = (const float4*)(W1 + (size_t)(mBase + i) * N0 + kc * 16);
#pragma unroll
    for (int j = 0; j < 4; ++j) w14[i][j] = r1[j];
  }

  float V[4]   = {0.f, 0.f, 0.f, 0.f};
  float A0v[4] = {0.f, 0.f, 0.f, 0.f};
  float A1v[4] = {0.f, 0.f, 0.f, 0.f};
  float Is[4]  = {0.f, 0.f, 0.f, 0.f};
  unsigned* cnt = bar + b * 32;    // one 128B line per batch (r5 win)

#pragma unroll 1
  for (int t = 0; t < T_STEPS; ++t) {
    // ===== phase 1: h1 / GLIF-A — depends only on S0 (no inter-WG data) ====
    {
      const float v2 = (t == 0) ? 0.f
                     : S0[(size_t)(t - 1) * (NB * N0) + b * N0 + tid];
      actO[(tid >> 4) * 20 + (tid & 15)] = v2;
    }
    __syncthreads();   // B1: actO staged

    float h1a[4] = {0.f, 0.f, 0.f, 0.f};
    const float4* aO4 = (const float4*)actO;
#pragma unroll
    for (int j = 0; j < 4; ++j) {
      const float4 a = aO4[kc * 5 + j];
#pragma unroll
      for (int i = 0; i < 4; ++i) {
        h1a[i] = fmaf(w14[i][j].x, a.x, h1a[i]);
        h1a[i] = fmaf(w14[i][j].y, a.y, h1a[i]);
        h1a[i] = fmaf(w14[i][j].z, a.z, h1a[i]);
        h1a[i] = fmaf(w14[i][j].w, a.w, h1a[i]);
      }
    }
#pragma unroll
    for (int mask = 1; mask <= 8; mask <<= 1) {
#pragma unroll
      for (int i = 0; i < 4; ++i) h1a[i] += __shfl_xor(h1a[i], mask, 64);
    }
    if (kc == 0) {
      float spa[4];
#pragma unroll
      for (int i = 0; i < 4; ++i) {
        Is[i] = fmaf(Is[i], C_SYN_D, C_SYN_I * h1a[i]);
        V[i]  = fmaf(V[i], C_V_D, C_KMR * (Is[i] + A0v[i] + A1v[i]));
        const float Sa = glif_S(V[i]);
        A0v[i] = fmaf(A0v[i], C_A0_D, C_A0_I * Sa);
        A1v[i] = fmaf(A1v[i], C_A1_D, C_A1_I * Sa);
        spa[i] = Sa;
      }
      float* outA = out + ((size_t)(2 * t) * NB + b) * N1 + mBase;
      *(float4*)outA = make_float4(spa[0], spa[1], spa[2], spa[3]);
    }

    // ===== spin: wait for all 8 WGs' spb_{t-1} (flag launched at end of
    // step t-1; it flew while we did phase 1). r5-verbatim machinery. =====
    if (t > 0) {
      if (tid == 0) {
        const unsigned tgt = 8u * (unsigned)t;
        while (__hip_atomic_load(cnt, __ATOMIC_RELAXED, __HIP_MEMORY_SCOPE_AGENT) < tgt) {}
      }
    }
    __syncthreads();   // B2: spin result visible; also fences phase-1 LDS

    // ===== phase 2: load spb_{t-1}, h2 / GLIF-B, store spb_t ====
    {
      float v0, v1;
      if (t == 0) {
        v0 = v1 = 0.f;
      } else {
        const float* pS = out + ((size_t)(2 * t - 1) * NB + b) * N1;
        v0 = __hip_atomic_load(pS + tid,       __ATOMIC_RELAXED, __HIP_MEMORY_SCOPE_AGENT);
        v1 = __hip_atomic_load(pS + tid + 256, __ATOMIC_RELAXED, __HIP_MEMORY_SCOPE_AGENT);
      }
      actS[(tid >> 5) * 36 + (tid & 31)] = v0;
      const int k = tid + 256;
      actS[(k >> 5) * 36 + (k & 31)] = v1;
    }
    __syncthreads();   // B3: actS staged

    float h2a[4] = {0.f, 0.f, 0.f, 0.f};
    const float4* aS4 = (const float4*)actS;
#pragma unroll
    for (int j = 0; j < 8; ++j) {
      const float4 a = aS4[kc * 9 + j];
#pragma unroll
      for (int i = 0; i < 4; ++i) {
        h2a[i] = fmaf(wr4[i][j].x, a.x, h2a[i]);
        h2a[i] = fmaf(wr4[i][j].y, a.y, h2a[i]);
        h2a[i] = fmaf(wr4[i][j].z, a.z, h2a[i]);
        h2a[i] = fmaf(wr4[i][j].w, a.w, h2a[i]);
      }
    }
#pragma unroll
    for (int mask = 1; mask <= 8; mask <<= 1) {
#pragma unroll
      for (int i = 0; i < 4; ++i) h2a[i] += __shfl_xor(h2a[i], mask, 64);
    }
    if (kc == 0) {
      float spb[4];
#pragma unroll
      for (int i = 0; i < 4; ++i) {
        Is[i] = fmaf(Is[i], C_SYN_D, C_SYN_I * h2a[i]);
        V[i]  = fmaf(V[i], C_V_D, C_KMR * (Is[i] + A0v[i] + A1v[i]));
        const float Sb = glif_S(V[i]);
        A0v[i] = fmaf(A0v[i], C_A0_D, C_A0_I * Sb);
        A1v[i] = fmaf(A1v[i], C_A1_D, C_A1_I * Sb);
        spb[i] = Sb;
      }
      // packed 8B write-through stores (same bytes as 4 dwords, half the
      // messages); consumers read them as floats next step.
      float* outB = out + ((size_t)(2 * t + 1) * NB + b) * N1 + mBase;
      const unsigned long long q0 =
          ((unsigned long long)__float_as_uint(spb[1]) << 32) | __float_as_uint(spb[0]);
      const unsigned long long q1 =
          ((unsigned long long)__float_as_uint(spb[3]) << 32) | __float_as_uint(spb[2]);
      __hip_atomic_store((unsigned long long*)outB,       q0,
                         __ATOMIC_RELAXED, __HIP_MEMORY_SCOPE_AGENT);
      __hip_atomic_store((unsigned long long*)(outB + 2), q1,
                         __ATOMIC_RELAXED, __HIP_MEMORY_SCOPE_AGENT);
    }

    // ===== signal completion of step t (r5-verbatim machinery) =====
    __syncthreads();  // B4: vmcnt(0) drain before s_barrier -> all waves'
                      // spb stores globally visible before the counter add.
    if (tid == 0) {
      __hip_atomic_fetch_add(cnt, 1u, __ATOMIC_RELAXED, __HIP_MEMORY_SCOPE_AGENT);
    }
    // The add flies to MALL while everyone proceeds into step t+1's phase 1.
  }
}

// ---------------------------------------------------------------------------
extern "C" void kernel_launch(void* const* d_in, const int* in_sizes, int n_in,
                              void* d_out, int out_size, void* d_ws, size_t ws_size,
                              hipStream_t stream) {
  const float* inputs = (const float*)d_in[0];   // [1000,32,1,256]
  const float* W1     = (const float*)d_in[1];   // [512,256]
  const float* Wr     = (const float*)d_in[2];   // [512,512]
  float* out = (float*)d_out;                    // [2000,32,1,512]

  float* S0 = (float*)d_ws;                                        // 32,768,000 B
  unsigned* bar = (unsigned*)((char*)d_ws +
                              (size_t)T_STEPS * NB * N0 * sizeof(float));

  // counters start at 0 every call; 32 batches x one 128B line each = 4KB.
  hipMemsetAsync(bar, 0, NB * 32 * sizeof(unsigned), stream);

  hipLaunchKernelGGL(layer0_scan, dim3((NB * N0) / 64), dim3(64), 0, stream,
                     inputs, S0);

  void* args[5];
  args[0] = (void*)&W1;
  args[1] = (void*)&Wr;
  args[2] = (void*)&S0;
  args[3] = (void*)&out;
  args[4] = (void*)&bar;
  // Cooperative launch: all 256 WGs (1/CU) co-resident -> counter spin
  // cannot deadlock.
  hipLaunchCooperativeKernel((const void*)rsnn_recur, dim3(256), dim3(256),
                             args, 0, stream);
}